// Round 11
// baseline (124.389 us; speedup 1.0000x reference)
//
#include <hip/hip_runtime.h>

// RPN anchor-target assignment. B=8, A=184320, G=64.
// Outputs (flat float32, concatenated): labels[B*A], matched[B*A*4], max_iou[B*A].
// Requires A % 1024 == 0 (184320 = 180*1024).
//
// Sparse-mask strategy, 4 anchors/thread SEQUENTIAL (R9: fusing chains doubles
// LDS conflicts; R10: float2 SoA + u64 loop regress — R8's 5xb32 SoA + two u32
// half-loops is the measured optimum; APT=4 amortizes wave prologue). 3
// kernels, no device fences (R6: per-block __threadfence() is an L2-flush-
// scale stall on CDNA4). Per batch, 4 quantized interval tables (u64[128],
// 5px strips, slack 0.01) give each anchor a conservative superset mask of
// possibly-overlapping gts; exact IEEE IoU only over mask bits (~10 avg).
// Skipped pairs have true iou==0: handled exactly by maxv init 0 / KEY_INIT.
// Column argmax via LDS u64 atomicMax (branchless zero key), block->global
// via device atomicMax on signed i64 (d_ws 0xAA poison < 0 == -inf).

constexpr int B = 8;
constexpr int G = 64;
constexpr int BLOCK = 256;
constexpr int APT = 4;                 // anchors per thread
constexpr int ABLK = BLOCK * APT;      // anchors per block = 1024
constexpr int NSTRIP = 128;            // 5px strips
constexpr float STRIP_SCALE = 0.2f;
constexpr float STRIP_W = 5.0f;
constexpr float IMG = 640.0f;
constexpr float FG_IOU = 0.7f;
constexpr float BG_IOU = 0.3f;
constexpr float SLACK = 0.01f;         // covers ~1e-4px strip-assign rounding
// key(iou=0, anchor=0): correct for an all-zero column (numpy argmax = 0).
constexpr unsigned long long KEY_INIT = 0xFFFFFFFFull;

// ws layout: [256]   i64 gkeys[B*G]      (0xAA poison < 0 as i64 == -inf)
//            [8192]  u64 tabs[B][4][128] (built by build_tables each launch)

// tab0 (xlo): gt.x0 < (s+1)*5 + SLACK   used at s=strip(ax1)  ⊇ gt.x0 < ax1
// tab1 (xhi): gt.x1 > s*5 - SLACK       used at s=strip(ax0)  ⊇ gt.x1 > ax0
// tab2 (ylo): gt.y0 < (s+1)*5 + SLACK   used at s=strip(ay1)  ⊇ gt.y0 < ay1
// tab3 (yhi): gt.y1 > s*5 - SLACK       used at s=strip(ay0)  ⊇ gt.y1 > ay0
__global__ __launch_bounds__(512) void build_tables(
    const float4* __restrict__ gt, unsigned long long* __restrict__ tabs) {
    __shared__ float4 sgt[G];
    const int b = blockIdx.x;
    const int t = threadIdx.x;          // 0..511 = tabIdx*128 + strip
    if (t < G) sgt[t] = gt[b * G + t];
    __syncthreads();
    const int tabIdx = t >> 7;
    const int strip = t & 127;
    const int comp = (tabIdx == 0) ? 0 : (tabIdx == 1) ? 2 : (tabIdx == 2) ? 1 : 3;
    const bool hi = (tabIdx & 1) != 0;
    const float thr = hi ? (strip * STRIP_W - SLACK)
                         : ((strip + 1) * STRIP_W + SLACK);
    unsigned long long m = 0ull;
    for (int g = 0; g < G; ++g) {
        float c = ((const float*)&sgt[g])[comp];
        bool in = hi ? (c > thr) : (c < thr);
        if (in) m |= (1ull << g);
    }
    tabs[(size_t)b * 512 + t] = m;
}

__global__ __launch_bounds__(BLOCK) void assign_main(
    const float4* __restrict__ anchors,   // [B*A] cxcywh
    const float4* __restrict__ gt,        // [B*G] xyxy
    float* __restrict__ L,                // labels out [B*A]
    float4* __restrict__ M,               // matched out [B*A]
    float* __restrict__ V,                // max_iou out [B*A]
    long long* __restrict__ gkeys,        // [B*G] global argmax keys (signed max)
    const unsigned long long* __restrict__ tabs,
    int A, int bpb) {
#pragma clang fp contract(off)
    __shared__ float4 sgt[G];             // AoS for the rare fg epilogue read
    __shared__ float sgx0[G], sgy0[G], sgx1[G], sgy1[G], sga[G];  // SoA b32
    __shared__ unsigned long long tab[4][NSTRIP];
    __shared__ unsigned long long skey[G];

    const int b = blockIdx.x / bpb;
    const int t = threadIdx.x;
    const int base = (blockIdx.x % bpb) * ABLK;

    if (t < G) {
        float4 gb = gt[b * G + t];
        sgt[t] = gb;
        sgx0[t] = gb.x; sgy0[t] = gb.y; sgx1[t] = gb.z; sgy1[t] = gb.w;
        sga[t] = (gb.z - gb.x) * (gb.w - gb.y);
        skey[t] = KEY_INIT;
    }
    {   // 4 KB table: two u64 per thread
        unsigned long long* tflat = &tab[0][0];
        const unsigned long long* src = tabs + (size_t)b * 512;
        tflat[t]       = src[t];
        tflat[t + 256] = src[t + 256];
    }
    __syncthreads();

#pragma unroll
    for (int j = 0; j < APT; ++j) {
        const int a = base + j * BLOCK + t;
        const size_t idx = (size_t)b * A + a;
        float4 an = anchors[idx];
        float ax0 = an.x - 0.5f * an.z;
        float ay0 = an.y - 0.5f * an.w;
        float ax1 = an.x + 0.5f * an.z;
        float ay1 = an.y + 0.5f * an.w;
        float area_a = (ax1 - ax0) * (ay1 - ay0);   // corner-derived, matches numpy

        int sx0 = (int)(ax0 * STRIP_SCALE); sx0 = sx0 < 0 ? 0 : (sx0 > 127 ? 127 : sx0);
        int sx1 = (int)(ax1 * STRIP_SCALE); sx1 = sx1 < 0 ? 0 : (sx1 > 127 ? 127 : sx1);
        int sy0 = (int)(ay0 * STRIP_SCALE); sy0 = sy0 < 0 ? 0 : (sy0 > 127 ? 127 : sy0);
        int sy1 = (int)(ay1 * STRIP_SCALE); sy1 = sy1 < 0 ? 0 : (sy1 > 127 ? 127 : sy1);

        unsigned long long mask =
            tab[0][sx1] & tab[1][sx0] & tab[2][sy1] & tab[3][sy0];

        float maxv = 0.0f;   // all-masked row => max_iou 0, argmax 0 (numpy exact)
        int maxg = 0;
        const unsigned long long inv_p =
            (unsigned long long)(0xFFFFFFFFu - (unsigned)a);

        // two u32 half-loops, ascending g => strict > keeps numpy first-max
        unsigned mlo = (unsigned)mask;
        unsigned mhi = (unsigned)(mask >> 32);
        auto half = [&](unsigned m, int gbase) {
            while (m) {
                const int g = gbase + __builtin_ctz(m);
                m &= m - 1;
                float gx0 = sgx0[g], gy0 = sgy0[g];
                float gx1 = sgx1[g], gy1 = sgy1[g];
                float sa = sga[g];
                float lx = fmaxf(ax0, gx0);
                float ly = fmaxf(ay0, gy0);
                float rx = fminf(ax1, gx1);
                float ry = fminf(ay1, gy1);
                float w = fmaxf(rx - lx, 0.0f);
                float h = fmaxf(ry - ly, 0.0f);
                float inter = w * h;
                float uni = area_a + sa - inter;
                float iou = inter / uni;         // IEEE div: bit-exact vs numpy

                bool better = iou > maxv;
                maxv = better ? iou : maxv;
                maxg = better ? g : maxg;

                unsigned long long key =
                    ((unsigned long long)__float_as_uint(iou) << 32) | inv_p;
                key = (iou > 0.0f) ? key : 0ull; // zero keys never beat KEY_INIT
                atomicMax(&skey[g], key);        // branchless, sparse contention
            }
        };
        half(mlo, 0);
        half(mhi, 32);

        bool fg = maxv > FG_IOU;
        bool bg = maxv < BG_IOU;
        bool cross = (ax0 < 0.0f) || (ay0 < 0.0f) || (ax1 > IMG) || (ay1 > IMG);

        L[idx] = cross ? -1.0f : (fg ? 1.0f : (bg ? 0.0f : -1.0f));
        float4 m = make_float4(0.0f, 0.0f, 0.0f, 0.0f);
        if (fg) m = sgt[maxg];                   // rare: usually whole-wave skipped
        M[idx] = m;
        V[idx] = maxv;
    }

    __syncthreads();
    if (t < G) {
        // unconditional: every column must receive >= KEY_INIT (gkeys poisoned)
        atomicMax(&gkeys[b * G + t], (long long)skey[t]);
    }
}

// Rule 1 fixup: one block per batch, thread per gt. numpy scatter is
// last-write-wins; thread g writes only if no later g' targets the same anchor.
__global__ void fixup(
    const float4* __restrict__ anchors,
    const float4* __restrict__ gt,
    const long long* __restrict__ gkeys,
    float* __restrict__ L,
    float4* __restrict__ M,
    const float* __restrict__ V,
    int A) {
#pragma clang fp contract(off)
    const int b = blockIdx.x;
    const int g = threadIdx.x;
    __shared__ int tgt[G];

    unsigned long long key = (unsigned long long)gkeys[b * G + g];
    unsigned int a = 0xFFFFFFFFu - (unsigned int)(key & 0xFFFFFFFFull);
    tgt[g] = (int)a;
    __syncthreads();

    bool write = true;
    for (int g2 = g + 1; g2 < G; ++g2)
        if (tgt[g2] == (int)a) { write = false; break; }
    if (!write) return;

    const size_t idx = (size_t)b * A + a;
    float4 an = anchors[idx];
    float ax0 = an.x - 0.5f * an.z;
    float ay0 = an.y - 0.5f * an.w;
    float ax1 = an.x + 0.5f * an.z;
    float ay1 = an.y + 0.5f * an.w;
    bool cross = (ax0 < 0.0f) || (ay0 < 0.0f) || (ax1 > IMG) || (ay1 > IMG);
    // Rule 1 label=1 overrides rule-3 bg; cross filter still wins.
    L[idx] = cross ? -1.0f : 1.0f;
    // Rule 2 (fg) overrides rule 1's matched box; otherwise rule 1 assigns gt[g].
    if (!(V[idx] > FG_IOU)) M[idx] = gt[b * G + g];
}

extern "C" void kernel_launch(void* const* d_in, const int* in_sizes, int n_in,
                              void* d_out, int out_size, void* d_ws, size_t ws_size,
                              hipStream_t stream) {
    const float4* anchors = (const float4*)d_in[0];
    const float4* gt      = (const float4*)d_in[1];
    const int A = in_sizes[0] / (B * 4);

    float* out = (float*)d_out;
    float*  L = out;                                 // [B*A]
    float4* M = (float4*)(out + (size_t)B * A);      // [B*A] float4
    float*  V = out + (size_t)B * A * 5;             // [B*A]

    char* ws = (char*)d_ws;
    long long* gkeys = (long long*)(ws + 256);       // poison 0xAA.. == -inf (i64)
    unsigned long long* tabs = (unsigned long long*)(ws + 8192);  // B*4*128 u64

    const int bpb = A / ABLK;                        // 184320/1024 = 180
    build_tables<<<B, 512, 0, stream>>>(gt, tabs);
    assign_main<<<B * bpb, BLOCK, 0, stream>>>(anchors, gt, L, M, V, gkeys,
                                               tabs, A, bpb);
    fixup<<<B, G, 0, stream>>>(anchors, gt, gkeys, L, M, V, A);
}

// Round 12
// 123.514 us; speedup vs baseline: 1.0071x; 1.0071x over previous
//
#include <hip/hip_runtime.h>

// RPN anchor-target assignment. B=8, A=184320, G=64.
// Outputs (flat float32, concatenated): labels[B*A], matched[B*A*4], max_iou[B*A].
// Requires A % 512 == 0 (184320 = 360*512).
//
// FINAL (session best = R8 structure, locked):
// Sparse-mask strategy, 2 anchors/thread sequential, 3 kernels.
//  - R1/R2: LDS same-address u64 atomics and per-gt butterflies are VALU-issue
//    poison in dense loops; rotation scheme got dense to 104 µs.
//  - R4: spatial sort gives sparsity but scattered concurrent output writes
//    cross XCDs are catastrophic (140 MB WRITE, 10x regression).
//  - R5/R7: interval-table masks give the same sparsity with fully coalesced
//    I/O; separate kernels beat per-block __threadfence (R6: fence == L2-flush
//    -scale stall on CDNA4).
//  - R9/R10/R11: chain fusion (2x conflicts), float2 SoA (2x conflicts),
//    u64 single loop, APT=4 — all neutral or regressions. R8 config is the
//    measured optimum: 5x b32 SoA reads, two u32 half-loops, branchless keys.
// Main kernel is VALU-issue-bound at ~46 µs (~90 slots/visited pair,
// calibrated across R3/R8/R10/R11). Remaining wall time is harness d_ws/d_out
// re-poison (~53 µs at 92% HBM roofline) + launch overhead — immovable.
//
// Exactness contract (absmax 0.0 across all passing rounds):
//  - IEEE fp32 div, fp-contract off; all compared quantities bit-match numpy.
//  - Interval masks are strict supersets (slack covers strip rounding);
//    skipped pairs have true iou==0, absorbed by maxv=0 / KEY_INIT.
//  - Column argmax key (iou_bits<<32)|(0xFFFFFFFF-a): monotone in iou (>=0),
//    ties -> lowest anchor (numpy argmax). Zero-iou keys never beat KEY_INIT,
//    KEY_INIT encodes (iou=0, anchor=0) = numpy argmax of an all-zero column.
//  - gkeys reduce via SIGNED i64 atomicMax: d_ws 0xAA poison < 0 == -inf.
//  - fixup replicates numpy scatter last-write-wins; rule-2 matched box beats
//    rule-1 when fg; rule-1 label beats rule-3 bg; cross-filter beats all.

constexpr int B = 8;
constexpr int G = 64;
constexpr int BLOCK = 256;
constexpr int APT = 2;                 // anchors per thread
constexpr int ABLK = BLOCK * APT;      // anchors per block
constexpr int NSTRIP = 128;            // 5px strips
constexpr float STRIP_SCALE = 0.2f;
constexpr float STRIP_W = 5.0f;
constexpr float IMG = 640.0f;
constexpr float FG_IOU = 0.7f;
constexpr float BG_IOU = 0.3f;
constexpr float SLACK = 0.01f;         // covers ~1e-4px strip-assign rounding
constexpr unsigned long long KEY_INIT = 0xFFFFFFFFull;

// ws layout: [256]   i64 gkeys[B*G]      (0xAA poison < 0 as i64 == -inf)
//            [8192]  u64 tabs[B][4][128] (built by build_tables each launch)

// tab0 (xlo): gt.x0 < (s+1)*5 + SLACK   used at s=strip(ax1)  ⊇ gt.x0 < ax1
// tab1 (xhi): gt.x1 > s*5 - SLACK       used at s=strip(ax0)  ⊇ gt.x1 > ax0
// tab2 (ylo): gt.y0 < (s+1)*5 + SLACK   used at s=strip(ay1)  ⊇ gt.y0 < ay1
// tab3 (yhi): gt.y1 > s*5 - SLACK       used at s=strip(ay0)  ⊇ gt.y1 > ay0
__global__ __launch_bounds__(512) void build_tables(
    const float4* __restrict__ gt, unsigned long long* __restrict__ tabs) {
    __shared__ float4 sgt[G];
    const int b = blockIdx.x;
    const int t = threadIdx.x;          // 0..511 = tabIdx*128 + strip
    if (t < G) sgt[t] = gt[b * G + t];
    __syncthreads();
    const int tabIdx = t >> 7;
    const int strip = t & 127;
    const int comp = (tabIdx == 0) ? 0 : (tabIdx == 1) ? 2 : (tabIdx == 2) ? 1 : 3;
    const bool hi = (tabIdx & 1) != 0;
    const float thr = hi ? (strip * STRIP_W - SLACK)
                         : ((strip + 1) * STRIP_W + SLACK);
    unsigned long long m = 0ull;
    for (int g = 0; g < G; ++g) {
        float c = ((const float*)&sgt[g])[comp];
        bool in = hi ? (c > thr) : (c < thr);
        if (in) m |= (1ull << g);
    }
    tabs[(size_t)b * 512 + t] = m;
}

__global__ __launch_bounds__(BLOCK) void assign_main(
    const float4* __restrict__ anchors,   // [B*A] cxcywh
    const float4* __restrict__ gt,        // [B*G] xyxy
    float* __restrict__ L,                // labels out [B*A]
    float4* __restrict__ M,               // matched out [B*A]
    float* __restrict__ V,                // max_iou out [B*A]
    long long* __restrict__ gkeys,        // [B*G] global argmax keys (signed max)
    const unsigned long long* __restrict__ tabs,
    int A, int bpb) {
#pragma clang fp contract(off)
    __shared__ float4 sgt[G];             // AoS for the rare fg epilogue read
    __shared__ float sgx0[G], sgy0[G], sgx1[G], sgy1[G], sga[G];  // SoA b32
    __shared__ unsigned long long tab[4][NSTRIP];
    __shared__ unsigned long long skey[G];

    const int b = blockIdx.x / bpb;
    const int t = threadIdx.x;
    const int base = (blockIdx.x % bpb) * ABLK;

    if (t < G) {
        float4 gb = gt[b * G + t];
        sgt[t] = gb;
        sgx0[t] = gb.x; sgy0[t] = gb.y; sgx1[t] = gb.z; sgy1[t] = gb.w;
        sga[t] = (gb.z - gb.x) * (gb.w - gb.y);
        skey[t] = KEY_INIT;
    }
    {   // 4 KB table: two u64 per thread
        unsigned long long* tflat = &tab[0][0];
        const unsigned long long* src = tabs + (size_t)b * 512;
        tflat[t]       = src[t];
        tflat[t + 256] = src[t + 256];
    }
    __syncthreads();

#pragma unroll
    for (int j = 0; j < APT; ++j) {
        const int a = base + j * BLOCK + t;
        const size_t idx = (size_t)b * A + a;
        float4 an = anchors[idx];
        float ax0 = an.x - 0.5f * an.z;
        float ay0 = an.y - 0.5f * an.w;
        float ax1 = an.x + 0.5f * an.z;
        float ay1 = an.y + 0.5f * an.w;
        float area_a = (ax1 - ax0) * (ay1 - ay0);   // corner-derived, matches numpy

        int sx0 = (int)(ax0 * STRIP_SCALE); sx0 = sx0 < 0 ? 0 : (sx0 > 127 ? 127 : sx0);
        int sx1 = (int)(ax1 * STRIP_SCALE); sx1 = sx1 < 0 ? 0 : (sx1 > 127 ? 127 : sx1);
        int sy0 = (int)(ay0 * STRIP_SCALE); sy0 = sy0 < 0 ? 0 : (sy0 > 127 ? 127 : sy0);
        int sy1 = (int)(ay1 * STRIP_SCALE); sy1 = sy1 < 0 ? 0 : (sy1 > 127 ? 127 : sy1);

        unsigned long long mask =
            tab[0][sx1] & tab[1][sx0] & tab[2][sy1] & tab[3][sy0];

        float maxv = 0.0f;   // all-masked row => max_iou 0, argmax 0 (numpy exact)
        int maxg = 0;
        const unsigned long long inv_p =
            (unsigned long long)(0xFFFFFFFFu - (unsigned)a);

        // two u32 half-loops, ascending g => strict > keeps numpy first-max
        unsigned mlo = (unsigned)mask;
        unsigned mhi = (unsigned)(mask >> 32);
        auto half = [&](unsigned m, int gbase) {
            while (m) {
                const int g = gbase + __builtin_ctz(m);
                m &= m - 1;
                float gx0 = sgx0[g], gy0 = sgy0[g];
                float gx1 = sgx1[g], gy1 = sgy1[g];
                float sa = sga[g];
                float lx = fmaxf(ax0, gx0);
                float ly = fmaxf(ay0, gy0);
                float rx = fminf(ax1, gx1);
                float ry = fminf(ay1, gy1);
                float w = fmaxf(rx - lx, 0.0f);
                float h = fmaxf(ry - ly, 0.0f);
                float inter = w * h;
                float uni = area_a + sa - inter;
                float iou = inter / uni;         // IEEE div: bit-exact vs numpy

                bool better = iou > maxv;
                maxv = better ? iou : maxv;
                maxg = better ? g : maxg;

                unsigned long long key =
                    ((unsigned long long)__float_as_uint(iou) << 32) | inv_p;
                key = (iou > 0.0f) ? key : 0ull; // zero keys never beat KEY_INIT
                atomicMax(&skey[g], key);        // branchless, sparse contention
            }
        };
        half(mlo, 0);
        half(mhi, 32);

        bool fg = maxv > FG_IOU;
        bool bg = maxv < BG_IOU;
        bool cross = (ax0 < 0.0f) || (ay0 < 0.0f) || (ax1 > IMG) || (ay1 > IMG);

        L[idx] = cross ? -1.0f : (fg ? 1.0f : (bg ? 0.0f : -1.0f));
        float4 m = make_float4(0.0f, 0.0f, 0.0f, 0.0f);
        if (fg) m = sgt[maxg];                   // rare: usually whole-wave skipped
        M[idx] = m;
        V[idx] = maxv;
    }

    __syncthreads();
    if (t < G) {
        // unconditional: every column must receive >= KEY_INIT (gkeys poisoned)
        atomicMax(&gkeys[b * G + t], (long long)skey[t]);
    }
}

// Rule 1 fixup: one block per batch, thread per gt. numpy scatter is
// last-write-wins; thread g writes only if no later g' targets the same anchor.
__global__ void fixup(
    const float4* __restrict__ anchors,
    const float4* __restrict__ gt,
    const long long* __restrict__ gkeys,
    float* __restrict__ L,
    float4* __restrict__ M,
    const float* __restrict__ V,
    int A) {
#pragma clang fp contract(off)
    const int b = blockIdx.x;
    const int g = threadIdx.x;
    __shared__ int tgt[G];

    unsigned long long key = (unsigned long long)gkeys[b * G + g];
    unsigned int a = 0xFFFFFFFFu - (unsigned int)(key & 0xFFFFFFFFull);
    tgt[g] = (int)a;
    __syncthreads();

    bool write = true;
    for (int g2 = g + 1; g2 < G; ++g2)
        if (tgt[g2] == (int)a) { write = false; break; }
    if (!write) return;

    const size_t idx = (size_t)b * A + a;
    float4 an = anchors[idx];
    float ax0 = an.x - 0.5f * an.z;
    float ay0 = an.y - 0.5f * an.w;
    float ax1 = an.x + 0.5f * an.z;
    float ay1 = an.y + 0.5f * an.w;
    bool cross = (ax0 < 0.0f) || (ay0 < 0.0f) || (ax1 > IMG) || (ay1 > IMG);
    // Rule 1 label=1 overrides rule-3 bg; cross filter still wins.
    L[idx] = cross ? -1.0f : 1.0f;
    // Rule 2 (fg) overrides rule 1's matched box; otherwise rule 1 assigns gt[g].
    if (!(V[idx] > FG_IOU)) M[idx] = gt[b * G + g];
}

extern "C" void kernel_launch(void* const* d_in, const int* in_sizes, int n_in,
                              void* d_out, int out_size, void* d_ws, size_t ws_size,
                              hipStream_t stream) {
    const float4* anchors = (const float4*)d_in[0];
    const float4* gt      = (const float4*)d_in[1];
    const int A = in_sizes[0] / (B * 4);

    float* out = (float*)d_out;
    float*  L = out;                                 // [B*A]
    float4* M = (float4*)(out + (size_t)B * A);      // [B*A] float4
    float*  V = out + (size_t)B * A * 5;             // [B*A]

    char* ws = (char*)d_ws;
    long long* gkeys = (long long*)(ws + 256);       // poison 0xAA.. == -inf (i64)
    unsigned long long* tabs = (unsigned long long*)(ws + 8192);  // B*4*128 u64

    const int bpb = A / ABLK;                        // 184320/512 = 360
    build_tables<<<B, 512, 0, stream>>>(gt, tabs);
    assign_main<<<B * bpb, BLOCK, 0, stream>>>(anchors, gt, L, M, V, gkeys,
                                               tabs, A, bpb);
    fixup<<<B, G, 0, stream>>>(anchors, gt, gkeys, L, M, V, A);
}